// Round 9
// baseline (188.649 us; speedup 1.0000x reference)
//
#include <hip/hip_runtime.h>
#include <hip/hip_bf16.h>
#include <hip/hip_fp8.h>

#define DIM 48
#define HS8 64            // fp8 row stride in BYTES (48 used, 64B sector aligned)
#define BKN 128           // nodes per bucket (pow2 -> shift/mask)
#define NB1MAX 800        // max buckets (N <= 102400)
#define NBLK 512          // partition blocks / chunks
#define BCAPE 3072        // LDS staging (edges) in k_sort; lambda=2048, +22 sigma
#define GNPB 32           // nodes per gather block (8 lanes/node, 256 thr)
#define SRCCAP 1024       // LDS srcs staging cap (block avg ~544, Poisson tail ~0)

typedef float v2f __attribute__((ext_vector_type(2)));

// ---- fp8 e4m3 helpers (HW cvt with header fallback) ----
__device__ inline unsigned pack_fp8x4(float a, float b, float c, float d) {
#if __has_builtin(__builtin_amdgcn_cvt_pk_fp8_f32)
    int w = __builtin_amdgcn_cvt_pk_fp8_f32(a, b, 0, false);
    w = __builtin_amdgcn_cvt_pk_fp8_f32(c, d, w, true);
    return (unsigned)w;
#else
    __hip_fp8_e4m3 qa(a), qb(b), qc(c), qd(d);
    return (unsigned)qa.__x | ((unsigned)qb.__x << 8) |
           ((unsigned)qc.__x << 16) | ((unsigned)qd.__x << 24);
#endif
}

__device__ inline void acc_fp8x4(unsigned w, float* acc) {
#if __has_builtin(__builtin_amdgcn_cvt_pk_f32_fp8)
    v2f lo = __builtin_amdgcn_cvt_pk_f32_fp8((int)w, false);
    v2f hi = __builtin_amdgcn_cvt_pk_f32_fp8((int)w, true);
    acc[0] += lo[0]; acc[1] += lo[1]; acc[2] += hi[0]; acc[3] += hi[1];
#else
    __hip_fp8_e4m3 q0, q1, q2, q3;
    q0.__x = (unsigned char)(w & 0xff);
    q1.__x = (unsigned char)((w >> 8) & 0xff);
    q2.__x = (unsigned char)((w >> 16) & 0xff);
    q3.__x = (unsigned char)(w >> 24);
    acc[0] += (float)q0; acc[1] += (float)q1;
    acc[2] += (float)q2; acc[3] += (float)q3;
#endif
}

// ---- pass 1: per-chunk bucket histogram bh[blk][b] ----
__global__ void k_bh(const int* __restrict__ col, int* __restrict__ bh, int E, int nb1) {
    __shared__ int h[NB1MAX];
    for (int i = threadIdx.x; i < nb1; i += blockDim.x) h[i] = 0;
    __syncthreads();
    int chunk = (E + NBLK - 1) / NBLK;
    int lo = blockIdx.x * chunk, hi = min(lo + chunk, E);
    for (int e = lo + threadIdx.x; e < hi; e += blockDim.x)
        atomicAdd(&h[col[e] >> 7], 1);
    __syncthreads();
    int* r = bh + (size_t)blockIdx.x * nb1;
    for (int i = threadIdx.x; i < nb1; i += blockDim.x) r[i] = h[i];
}

// ---- pass 2: per-bucket column scan over the NBLK chunks ----
__global__ void k_colscan(int* __restrict__ bh, int* __restrict__ coltot, int nb1) {
    __shared__ int sm[NBLK];
    int b = blockIdx.x, t = threadIdx.x;
    sm[t] = bh[(size_t)t * nb1 + b];
    __syncthreads();
    int val = sm[t];
    for (int off = 1; off < NBLK; off <<= 1) {
        int v = (t >= off) ? sm[t - off] : 0;
        __syncthreads();
        sm[t] += v;
        __syncthreads();
    }
    bh[(size_t)t * nb1 + b] = sm[t] - val;   // exclusive within column
    if (t == NBLK - 1) coltot[b] = sm[t];
}

// ---- pass 3: bucket-level scan -> bstart; zero g; nodeoff[N]=E ----
__global__ void k_scan1(const int* __restrict__ coltot, int* __restrict__ bstart,
                        float* __restrict__ g, int* __restrict__ nodeoff,
                        int nb1, int N, int E) {
    __shared__ int sm[1024];
    int t = threadIdx.x;
    sm[t] = (t < nb1) ? coltot[t] : 0;
    __syncthreads();
    for (int off = 1; off < 1024; off <<= 1) {
        int v = (t >= off) ? sm[t - off] : 0;
        __syncthreads();
        sm[t] += v;
        __syncthreads();
    }
    if (t < nb1) bstart[t] = (t == 0) ? 0 : sm[t - 1];
    if (t == 0) { bstart[nb1] = E; nodeoff[N] = E; }
    if (t < 64) g[t] = 0.0f;
}

// ---- pass 4: single-pass scatter into bucketed 'part' (packed lcol<<24|row) ----
__global__ void k_part2(const int* __restrict__ row, const int* __restrict__ col,
                        const int* __restrict__ bh, const int* __restrict__ bstart,
                        unsigned* __restrict__ part, int E, int nb1) {
    __shared__ int base[NB1MAX];
    __shared__ int lcur[NB1MAX];
    int blk = blockIdx.x, t = threadIdx.x;
    const int* bhr = bh + (size_t)blk * nb1;
    for (int i = t; i < nb1; i += blockDim.x) { base[i] = bstart[i] + bhr[i]; lcur[i] = 0; }
    __syncthreads();
    int chunk = (E + NBLK - 1) / NBLK;
    int lo = blk * chunk, hi = min(lo + chunk, E);
    for (int e = lo + t; e < hi; e += blockDim.x) {
        int c = col[e], r = row[e];
        int b = c >> 7;
        int s = atomicAdd(&lcur[b], 1);
        part[base[b] + s] = ((unsigned)(c & 127) << 24) | (unsigned)r;
    }
}

// ---- pass 5: per-bucket counting sort -> exact CSR srcs/nodeoff + dinv ----
__global__ void k_sort(const unsigned* __restrict__ part, const int* __restrict__ bstart,
                       int* __restrict__ nodeoff, float* __restrict__ dinv,
                       int* __restrict__ srcs, int N, int nb1) {
    __shared__ int cnt[BKN];
    __shared__ int cur[BKN];
    __shared__ int sc[256];
    __shared__ int outb[BCAPE];
    int b = blockIdx.x, t = threadIdx.x;
    int nlo = b * BKN;
    int elo = bstart[b], ehi = bstart[b + 1];
    int nE = ehi - elo;
    if (t < BKN) cnt[t] = 0;
    __syncthreads();
    for (int e = elo + t; e < ehi; e += blockDim.x)
        atomicAdd(&cnt[part[e] >> 24], 1);
    __syncthreads();
    int v = (t < BKN) ? cnt[t] : 0;
    sc[t] = v;
    __syncthreads();
    for (int off = 1; off < 256; off <<= 1) {
        int u = (t >= off) ? sc[t - off] : 0;
        __syncthreads();
        sc[t] += u;
        __syncthreads();
    }
    int ex = (t == 0) ? 0 : sc[t - 1];
    if (t < BKN && nlo + t < N) {
        nodeoff[nlo + t] = elo + ex;
        dinv[nlo + t] = 1.0f / sqrtf((float)(v + 1));
        cur[t] = ex;
    }
    __syncthreads();
    if (nE <= BCAPE) {
        for (int e = elo + t; e < ehi; e += blockDim.x) {
            unsigned p = part[e];
            int s = atomicAdd(&cur[p >> 24], 1);
            outb[s] = (int)(p & 0xffffffu);
        }
        __syncthreads();
        for (int i = t; i < nE; i += blockDim.x) srcs[elo + i] = outb[i];
    } else {  // overflow fallback (statistically unreachable)
        for (int e = elo + t; e < ehi; e += blockDim.x) {
            unsigned p = part[e];
            int s = atomicAdd(&cur[p >> 24], 1);
            srcs[elo + s] = (int)(p & 0xffffffu);
        }
    }
}

// hs8[i,:] = fp8_e4m3( (in[i,:] @ W) * dinv[i] ), 64B-padded rows
__global__ void k_mm_scale(const float* __restrict__ in, const float* __restrict__ W,
                           const float* __restrict__ dinv,
                           unsigned char* __restrict__ hs8, int n) {
    __shared__ float Ws[DIM * DIM];
    for (int i = threadIdx.x; i < DIM * DIM; i += blockDim.x) Ws[i] = W[i];
    __syncthreads();
    int node = blockIdx.x * blockDim.x + threadIdx.x;
    if (node >= n) return;
    float xr[DIM];
    const float4* xp = (const float4*)(in + (size_t)node * DIM);
    #pragma unroll
    for (int j = 0; j < DIM / 4; ++j) {
        float4 v = xp[j];
        xr[j * 4 + 0] = v.x; xr[j * 4 + 1] = v.y;
        xr[j * 4 + 2] = v.z; xr[j * 4 + 3] = v.w;
    }
    float o[DIM];
    #pragma unroll
    for (int f = 0; f < DIM; ++f) o[f] = 0.0f;
    for (int k = 0; k < DIM; ++k) {
        float xv = xr[k];
        #pragma unroll
        for (int f = 0; f < DIM; ++f) o[f] = fmaf(xv, Ws[k * DIM + f], o[f]);
    }
    float d = dinv[node];
    uint4* hp = (uint4*)(hs8 + (size_t)node * HS8);
    #pragma unroll
    for (int q = 0; q < 3; ++q) {
        uint4 v;
        v.x = pack_fp8x4(o[q*16+ 0]*d, o[q*16+ 1]*d, o[q*16+ 2]*d, o[q*16+ 3]*d);
        v.y = pack_fp8x4(o[q*16+ 4]*d, o[q*16+ 5]*d, o[q*16+ 6]*d, o[q*16+ 7]*d);
        v.z = pack_fp8x4(o[q*16+ 8]*d, o[q*16+ 9]*d, o[q*16+10]*d, o[q*16+11]*d);
        v.w = pack_fp8x4(o[q*16+12]*d, o[q*16+13]*d, o[q*16+14]*d, o[q*16+15]*d);
        hp[q] = v;
    }
}

// Node-parallel gather v2: 8 lanes/node = 2 edge-groups x 4 chunk-lanes (12B dwordx3
// each), LDS-staged srcs, shfl_down(4) combine. Virtual list: k=0 self, k>=1 edges.
// RELU=1: outp[i,:] = leaky(dinv[i]*sum + bias).  RELU=0: g[f] += dinv[i]*sum.
template <int RELU>
__global__ __launch_bounds__(GNPB * 8) void k_gather(
    const unsigned char* __restrict__ hs8,
    const int* __restrict__ nodeoff, const int* __restrict__ srcs,
    const float* __restrict__ dinv, const float* __restrict__ bias,
    float* __restrict__ outp, float* __restrict__ g, int n) {
    __shared__ int s_srcs[SRCCAP];
    __shared__ float gsum[DIM];
    int t = threadIdx.x;
    if (!RELU && t < DIM) gsum[t] = 0.0f;
    int nlo = blockIdx.x * GNPB;
    int nhi = min(nlo + GNPB, n);
    int segbase = nodeoff[nlo];
    int seglen = nodeoff[nhi] - segbase;
    bool staged = (seglen <= SRCCAP);
    if (staged)
        for (int u = t; u < seglen; u += GNPB * 8) s_srcs[u] = srcs[segbase + u];
    __syncthreads();

    int local = t >> 3;                // node within block
    int sub = t & 7;
    int grp = sub >> 2;                // 0/1: even/odd virtual indices
    int c = sub & 3;                   // 12B chunk 0..3
    int i = nlo + local;
    bool valid = (i < n);
    float acc[12];
    #pragma unroll
    for (int k = 0; k < 12; ++k) acc[k] = 0.0f;
    float d = 0.0f;
    if (valid) {
        int start = nodeoff[i];
        int end = nodeoff[i + 1];
        int deg = end - start;
        int lbase = start - segbase;
        d = dinv[i];
        const unsigned char* hb = hs8 + (size_t)c * 12;
        for (int k = grp; k <= deg; k += 2) {
            int src;
            if (k == 0) src = i;
            else src = staged ? s_srcs[lbase + k - 1] : srcs[start + k - 1];
            uint3 v = *(const uint3*)(hb + (size_t)src * HS8);
            acc_fp8x4(v.x, acc + 0);
            acc_fp8x4(v.y, acc + 4);
            acc_fp8x4(v.z, acc + 8);
        }
    }
    // combine the two edge-groups: lanes sub<4 <- += lanes sub+4
    #pragma unroll
    for (int k = 0; k < 12; ++k) acc[k] += __shfl_down(acc[k], 4);

    if (RELU) {
        if (valid && grp == 0) {
            float o[12];
            #pragma unroll
            for (int k = 0; k < 12; ++k) {
                float v = acc[k] * d + bias[c * 12 + k];
                o[k] = (v >= 0.0f) ? v : 0.01f * v;
            }
            float4* op = (float4*)(outp + (size_t)i * DIM + c * 12);
            op[0] = make_float4(o[0], o[1], o[2], o[3]);
            op[1] = make_float4(o[4], o[5], o[6], o[7]);
            op[2] = make_float4(o[8], o[9], o[10], o[11]);
        }
    } else {
        if (valid && grp == 0) {
            #pragma unroll
            for (int k = 0; k < 12; ++k) atomicAdd(&gsum[c * 12 + k], acc[k] * d);
        }
        __syncthreads();
        if (t < DIM) atomicAdd(&g[t], gsum[t]);
    }
}

// out[k] = sum_f (g[f] + n*b2[f]) * Wlin[f,k] + blin[k]
__global__ void k_final(const float* __restrict__ g, const float* __restrict__ b2,
                        const float* __restrict__ Wlin, const float* __restrict__ blin,
                        float* __restrict__ out, int n) {
    int k = threadIdx.x;
    if (k < 2) {
        float s = blin[k];
        for (int f = 0; f < DIM; ++f)
            s += (g[f] + (float)n * b2[f]) * Wlin[f * 2 + k];
        out[k] = s;
    }
}

static inline char* alignup(char* p, size_t a) {
    return (char*)(((uintptr_t)p + a - 1) & ~(uintptr_t)(a - 1));
}

extern "C" void kernel_launch(void* const* d_in, const int* in_sizes, int n_in,
                              void* d_out, int out_size, void* d_ws, size_t ws_size,
                              hipStream_t stream) {
    const float* x    = (const float*)d_in[0];
    const int*   ei   = (const int*)d_in[1];
    const float* W1   = (const float*)d_in[2];
    const float* b1   = (const float*)d_in[3];
    const float* W2   = (const float*)d_in[4];
    const float* b2   = (const float*)d_in[5];
    const float* Wlin = (const float*)d_in[6];
    const float* blin = (const float*)d_in[7];
    float* out = (float*)d_out;

    int N = in_sizes[0] / DIM;
    int E = in_sizes[1] / 2;
    const int* row = ei;
    const int* col = ei + E;
    int nb1 = (N + BKN - 1) / BKN;   // 782 for N=100k (<= NB1MAX)

    // workspace layout (64B-aligned slices)
    char* p = (char*)d_ws;
    int* bh = (int*)p;                    p = alignup(p + (size_t)NBLK * nb1 * 4, 64);
    int* coltot = (int*)p;                p = alignup(p + nb1 * 4, 64);
    int* bstart = (int*)p;                p = alignup(p + (nb1 + 1) * 4, 64);
    int* nodeoff = (int*)p;               p = alignup(p + (size_t)(N + 1) * 4, 64);
    float* dinv = (float*)p;              p = alignup(p + (size_t)N * 4, 64);
    float* g = (float*)p;                 p = alignup(p + 64 * 4, 64);
    unsigned* part = (unsigned*)p;        p = alignup(p + (size_t)E * 4, 64);
    int* srcs = (int*)p;                  p = alignup(p + (size_t)E * 4, 64);
    unsigned char* hs8 = (unsigned char*)p; p = alignup(p + (size_t)N * HS8, 64);
    float* bufh = (float*)p;              // N*DIM f32

    int nblk = (N + 255) / 256;
    int gblk = (N + GNPB - 1) / GNPB;

    // deterministic two-level partition + per-bucket sort (shared by both layers)
    k_bh<<<NBLK, 256, 0, stream>>>(col, bh, E, nb1);
    k_colscan<<<nb1, NBLK, 0, stream>>>(bh, coltot, nb1);
    k_scan1<<<1, 1024, 0, stream>>>(coltot, bstart, g, nodeoff, nb1, N, E);
    k_part2<<<NBLK, 256, 0, stream>>>(row, col, bh, bstart, part, E, nb1);
    k_sort<<<nb1, 256, 0, stream>>>(part, bstart, nodeoff, dinv, srcs, N, nb1);

    // layer 1
    k_mm_scale<<<nblk, 256, 0, stream>>>(x, W1, dinv, hs8, N);
    k_gather<1><<<gblk, GNPB * 8, 0, stream>>>(hs8, nodeoff, srcs, dinv, b1, bufh, g, N);

    // layer 2 (global pool fused; bias folded into k_final)
    k_mm_scale<<<nblk, 256, 0, stream>>>(bufh, W2, dinv, hs8, N);
    k_gather<0><<<gblk, GNPB * 8, 0, stream>>>(hs8, nodeoff, srcs, dinv, b2, bufh, g, N);

    // final linear
    k_final<<<1, 64, 0, stream>>>(g, b2, Wlin, blin, out, N);
}